// Round 9
// baseline (75.382 us; speedup 1.0000x reference)
//
#include <hip/hip_runtime.h>
#include <math.h>

#define SZ 256
#define KNN 4
#define NUM_CHANNELS 8
#define R 7                  // main window half-width; exact iff 4th d2 < 64
#define WROWS (2 * R + 1)    // 15 main rows (clamped to image)
#define FR 16                // staged row half-range for fallback
#define FROWS (2 * FR + 1)   // 33 staged rows; unstaged rows have d2 >= 289
#define RSTRIDE 6            // LDS row: [zero pad][4 words][zero pad]

typedef unsigned long long u64;
typedef unsigned int u32;

// Branchless insert into ascending sorted 4 (u32 keys).
// key = (d2 << 16) | flat_idx; main-loop d2 <= 245 -> no overflow.
// Matches jax.lax.top_k ordering incl. lower-index tie-break.
__device__ __forceinline__ void ins4(u32 key, u32& k0, u32& k1,
                                     u32& k2, u32& k3) {
    u32 m;
    m = (k2 > key) ? k2 : key;  k3 = (k3 < m) ? k3 : m;   // old k2
    m = (k1 > key) ? k1 : key;  k2 = (k2 < m) ? k2 : m;   // old k1
    m = (k0 > key) ? k0 : key;  k1 = (k1 < m) ? k1 : m;   // old k0
    k0 = (k0 < key) ? k0 : key;
}

// u64 variant for fallbacks (d2 up to 130050 would overflow a u32 key).
__device__ __forceinline__ void ins4_64(u64 key, u64& k0, u64& k1,
                                        u64& k2, u64& k3) {
    if (key < k3) {
        u64 m;
        m = (k2 > key) ? k2 : key;  k3 = (k3 < m) ? k3 : m;
        m = (k1 > key) ? k1 : key;  k2 = (k2 < m) ? k2 : m;
        m = (k0 > key) ? k0 : key;  k1 = (k1 < m) ? k1 : m;
        k0 = (k0 < key) ? k0 : key;
    }
}

// Single fused kernel:
//  - ballot-build the 15 main rows into LDS (per-block, per-channel)
//  - wave-uniform |dy|-ordered main scan, u32 keys, __all early break
//  - block-level vote: ~3% of blocks build 18 more rows and run the LDS
//    secondary fallback; tertiary elementwise scan ~never fires.
__global__ __launch_bounds__(256) void knn_fill(
    const float* __restrict__ img,
    const int*   __restrict__ lut,
    float*       __restrict__ out)
{
    __shared__ u64 win[FROWS * RSTRIDE];   // 1584 B padded window bitmap
    __shared__ int fbflag;

    const int x    = threadIdx.x;
    const int y    = blockIdx.x;           // block-uniform -> uniform loops
    const int ch   = blockIdx.y;
    const int c    = ch + 1;
    const int lane = x & 63;
    const int w64  = x >> 6;

    // Clamped staged-window start (33 full in-image rows).
    int y0b = y - FR;
    if (y0b < 0) y0b = 0;
    if (y0b > SZ - FROWS) y0b = SZ - FROWS;
    // Clamped main-window start (15 full in-image rows).
    int y0m = y - R;
    if (y0m < 0) y0m = 0;
    if (y0m > SZ - WROWS) y0m = SZ - WROWS;
    const int m0 = y0m - y0b;              // main rows offset in staged buf

    // Zero all 66 pad words; init vote flag.
    if (x < FROWS * 2) win[(x >> 1) * RSTRIDE + (x & 1) * 5] = 0;
    if (x == 0) fbflag = 0;

    // Ballot-build only the 15 main rows (all 256 threads active).
    #pragma unroll
    for (int rr = 0; rr < WROWS; ++rr) {
        const int v = lut[(y0m + rr) * SZ + x];
        const u64 bal = __ballot(v == c);
        if (lane == 0) win[(m0 + rr) * RSTRIDE + 1 + w64] = bal;
    }
    __syncthreads();

    const int pix = y * SZ + x;
    float* outc = out + (size_t)ch * (SZ * SZ);

    const bool filled =
        (win[(y - y0b) * RSTRIDE + 1 + (x >> 6)] >> (x & 63)) & 1ull;

    u32 k0 = ~0u, k1 = ~0u, k2 = ~0u, k3 = ~0u;

    const int base = x - R + 64;    // bit offset into padded row
    const int wrd  = base >> 6;     // 0..4
    const int sh   = base & 63;

    if (!filled) {
        // Main scan, rows ordered by |dy| (block-uniform control flow).
        for (int ady = 0; ady < WROWS; ++ady) {
            #pragma unroll
            for (int s = 0; s < 2; ++s) {
                if (s && ady == 0) continue;
                const int yy = s ? y + ady : y - ady;
                const int rr = yy - y0m;
                if (rr < 0 || rr >= WROWS) continue;   // outside clamped win
                const int rr2 = m0 + rr;
                const u64 lo = win[rr2 * RSTRIDE + wrd];
                const u64 hi = win[rr2 * RSTRIDE + wrd + 1];
                u32 w = (u32)((u64)(((((unsigned __int128)hi) << 64) | lo)
                                    >> sh)) & ((1u << WROWS) - 1);
                const int dy2  = ady * ady;
                const int rowx = yy * SZ + x;
                while (w) {
                    const int b = __builtin_ctz(w);
                    w &= w - 1;
                    const int dx  = b - R;
                    const u32 d2  = (u32)(dy2 + dx * dx);      // <= 245
                    const u32 key = (d2 << 16) | (u32)(rowx + dx);
                    ins4(key, k0, k1, k2, k3);
                }
            }
            // Remaining rows have |dy| >= ady+1 -> d2 >= (ady+1)^2 > k3_d2
            // for every active lane -> all further inserts no-ops.
            if (__all((k3 >> 16) < (u32)((ady + 1) * (ady + 1)))) break;
        }
    }

    const u32 in_d2 = k3 >> 16;
    // Exactness: any cell outside (15 main rows ∧ |dx|<=7) has d2 >= 64.
    const bool need = !filled && in_d2 >= (u32)((R + 1) * (R + 1));
    if (need) fbflag = 1;                  // benign race, same value
    __syncthreads();

    if (fbflag) {
        // Block-uniform: cooperatively build the 18 non-main staged rows.
        #pragma unroll
        for (int rr = 0; rr < FROWS; ++rr) {
            if (rr >= m0 && rr < m0 + WROWS) continue;   // keep main rows
            const int v = lut[(y0b + rr) * SZ + x];
            const u64 bal = __ballot(v == c);
            if (lane == 0) win[rr * RSTRIDE + 1 + w64] = bal;
        }
        __syncthreads();
    }

    if (filled) {
        outc[pix] = img[pix];              // no barriers after this point
        return;
    }

    u64 ks[KNN];
    if (!need) {
        ks[0] = k0; ks[1] = k1; ks[2] = k2; ks[3] = k3;  // same bit format
    } else {
        // Secondary fallback: cap-pruned ring ctz scan over the staged
        // 33-row LDS bitmap, u64 keys. cap = in-window 4th-best d2 (0xFFFF
        // if <4 found) — valid upper bound; a2<=cur / Rx+1 conservatism
        // keeps tie-breaks exact.
        const u64 cap = (u64)in_d2;
        u64 q0 = ~0ull, q1 = ~0ull, q2 = ~0ull, q3 = ~0ull;
        for (int ady = 0; ady < FROWS; ++ady) {
            u64 cur = q3 >> 16;
            if (cap < cur) cur = cap;
            const u64 a2 = (u64)(ady * ady);
            if (a2 > cur) break;          // keep a2 == cur (ties)
            const u64 bound = cur - a2;
            int Rx = (bound >= 65025ull) ? (SZ - 1)
                                         : ((int)sqrtf((float)bound) + 1);
            int xs = x - Rx; if (xs < 0) xs = 0;
            int xe = x + Rx; if (xe > SZ - 1) xe = SZ - 1;
            const int jxs = xs >> 6, jxe = xe >> 6;
            const u64 mlo = (~0ull) << (xs & 63);
            const u64 mhi = (~0ull) >> (63 - (xe & 63));
            #pragma unroll
            for (int s = 0; s < 2; ++s) {
                if (s && ady == 0) continue;
                const int yy = s ? y + ady : y - ady;
                const int rr2 = yy - y0b;
                if (rr2 < 0 || rr2 >= FROWS) continue;   // unstaged: d2>=289
                const int rb = yy * SZ;
                const u64* rw = &win[rr2 * RSTRIDE + 1];
                for (int j = jxs; j <= jxe; ++j) {
                    u64 w = rw[j];
                    if (j == jxs) w &= mlo;
                    if (j == jxe) w &= mhi;
                    while (w) {
                        const int b = __builtin_ctzll(w);
                        w &= w - 1;
                        const int xx = (j << 6) + b;
                        const int dxx = xx - x;
                        const u64 d2 = a2 + (u64)(dxx * dxx);
                        ins4_64((d2 << 16) | (u32)(rb + xx), q0, q1, q2, q3);
                    }
                }
            }
        }
        // Cells outside the staged rows have |dy| >= 17 -> d2 >= 289.
        if ((q3 >> 16) < 289ull) {
            ks[0] = q0; ks[1] = q1; ks[2] = q2; ks[3] = q3;
        } else {
            // Tertiary (correctness guarantee; ~never fires): full-image
            // cap-pruned elementwise ring scan over lut, u64 keys.
            const u64 cap2 = q3 >> 16;
            u64 t0 = ~0ull, t1 = ~0ull, t2 = ~0ull, t3 = ~0ull;
            for (int ady = 0; ady < SZ; ++ady) {
                u64 cur = t3 >> 16;
                if (cap2 < cur) cur = cap2;
                const u64 a2 = (u64)(ady * ady);
                if (a2 > cur) break;
                const u64 bound = cur - a2;
                int Rx = (bound >= 65025ull) ? (SZ - 1)
                                             : ((int)sqrtf((float)bound) + 1);
                int xs = x - Rx; if (xs < 0) xs = 0;
                int xe = x + Rx; if (xe > SZ - 1) xe = SZ - 1;
                for (int s = 0; s < 2; ++s) {
                    if (s && ady == 0) continue;
                    const int yy = s ? y + ady : y - ady;
                    if (yy < 0 || yy > SZ - 1) continue;
                    const int rb = yy * SZ;
                    for (int xx = xs; xx <= xe; ++xx) {
                        if (lut[rb + xx] == c) {
                            const int dxx = xx - x;
                            const u64 d2 = a2 + (u64)(dxx * dxx);
                            ins4_64((d2 << 16) | (u32)(rb + xx),
                                    t0, t1, t2, t3);
                        }
                    }
                }
            }
            ks[0] = t0; ks[1] = t1; ks[2] = t2; ks[3] = t3;
        }
    }

    // Weighted sum in top_k order (ascending (d2, idx)), matching reference.
    float num = 0.0f, den = 0.0f;
    #pragma unroll
    for (int i = 0; i < KNN; ++i) {
        const int idx = (int)(ks[i] & 0xFFFFull);
        const int d2i = (int)(ks[i] >> 16);
        const float dist = sqrtf((float)d2i * (1.0f / 65536.0f));
        num += img[idx] * dist;
        den += dist;
    }
    outc[pix] = num / den;
}

extern "C" void kernel_launch(void* const* d_in, const int* in_sizes, int n_in,
                              void* d_out, int out_size, void* d_ws, size_t ws_size,
                              hipStream_t stream) {
    const float* img = (const float*)d_in[0];   // coded: [1,1,256,256] f32
    const int*   lut = (const int*)d_in[1];     // lookup_table: [256,256] i32
    float*       out = (float*)d_out;           // [1,8,256,256] f32

    knn_fill<<<dim3(SZ, NUM_CHANNELS), dim3(256), 0, stream>>>(img, lut, out);
}

// Round 10
// 74.726 us; speedup vs baseline: 1.0088x; 1.0088x over previous
//
#include <hip/hip_runtime.h>
#include <math.h>

#define SZ 256
#define KNN 4
#define NUM_CHANNELS 8
#define R 7                  // main window half-width; exact iff 4th d2 < 64
#define WROWS (2 * R + 1)    // 15 main rows (clamped to image)
#define FR 16                // staged row half-range
#define FROWS (2 * FR + 1)   // 33 staged rows; unstaged rows have d2 >= 289
#define RSTRIDE 6            // LDS row: [zero pad][4 words][zero pad]

typedef unsigned long long u64;
typedef unsigned int u32;

// Guarded branchless insert into ascending sorted 4 (u32 keys).
// key = (d2 << 16) | flat_idx; main-loop d2 <= 245 -> no overflow.
// Matches jax.lax.top_k ordering incl. lower-index tie-break.
// Guard: key >= k3 makes the network a provable no-op -> skip (exec-masked).
__device__ __forceinline__ void ins4(u32 key, u32& k0, u32& k1,
                                     u32& k2, u32& k3) {
    if (key < k3) {
        u32 m;
        m = (k2 > key) ? k2 : key;  k3 = (k3 < m) ? k3 : m;   // old k2
        m = (k1 > key) ? k1 : key;  k2 = (k2 < m) ? k2 : m;   // old k1
        m = (k0 > key) ? k0 : key;  k1 = (k1 < m) ? k1 : m;   // old k0
        k0 = (k0 < key) ? k0 : key;
    }
}

// u64 variant for fallbacks (d2 up to 130050 would overflow a u32 key).
__device__ __forceinline__ void ins4_64(u64 key, u64& k0, u64& k1,
                                        u64& k2, u64& k3) {
    if (key < k3) {
        u64 m;
        m = (k2 > key) ? k2 : key;  k3 = (k3 < m) ? k3 : m;
        m = (k1 > key) ? k1 : key;  k2 = (k2 < m) ? k2 : m;
        m = (k0 > key) ? k0 : key;  k1 = (k1 < m) ? k1 : m;
        k0 = (k0 < key) ? k0 : key;
    }
}

// Pass 1: per-channel occupancy bitmaps via wave ballot.
// bm layout: u64[NUM_CHANNELS][SZ][4]; word j covers x in [j*64, j*64+64).
__global__ __launch_bounds__(256) void build_bitmaps(
    const int* __restrict__ lut,
    u64* __restrict__ bm)
{
    const int y = blockIdx.x;
    const int x = threadIdx.x;
    const int v = lut[y * SZ + x];
    const int lane = x & 63;
    const int w64 = x >> 6;
    #pragma unroll
    for (int c = 1; c <= NUM_CHANNELS; ++c) {
        u64 bal = __ballot(v == c);
        if (lane == 0) bm[(size_t)(c - 1) * (SZ * 4) + y * 4 + w64] = bal;
    }
}

// Pass 2: stage 33 clamped rows from the global bitmap into LDS; straight
// fully-unrolled 15-row scan (u32 keys, guarded insert); rare LDS secondary
// fallback (u64 keys); ~never tertiary over the global bitmap.
__global__ __launch_bounds__(256) void knn_fill(
    const float* __restrict__ img,
    const u64*   __restrict__ bm,
    float*       __restrict__ out)
{
    __shared__ u64 win[FROWS * RSTRIDE];   // 1584 B padded window bitmap

    const int x   = threadIdx.x;
    const int y   = blockIdx.x;            // block-uniform -> uniform loops
    const int ch  = blockIdx.y;
    const int tid = threadIdx.x;
    const u64* bmc = bm + (size_t)ch * (SZ * 4);

    // Clamped staged-window start (33 full in-image rows).
    int y0b = y - FR;
    if (y0b < 0) y0b = 0;
    if (y0b > SZ - FROWS) y0b = SZ - FROWS;
    // Clamped main-window start (15 full in-image rows).
    int y0m = y - R;
    if (y0m < 0) y0m = 0;
    if (y0m > SZ - WROWS) y0m = SZ - WROWS;
    const int m0 = y0m - y0b;              // main rows offset in staged buf

    // Zero the 66 pad words; load the 132 contiguous bitmap words.
    if (tid < FROWS * 2) win[(tid >> 1) * RSTRIDE + (tid & 1) * 5] = 0;
    if (tid < FROWS * 4) {
        const int rr = tid >> 2, j = tid & 3;
        win[rr * RSTRIDE + 1 + j] = bmc[(y0b + rr) * 4 + j];
    }
    __syncthreads();

    const int pix = y * SZ + x;
    float* outc = out + (size_t)ch * (SZ * SZ);

    if ((win[(y - y0b) * RSTRIDE + 1 + (x >> 6)] >> (x & 63)) & 1ull) {
        outc[pix] = img[pix];
        return;
    }

    u32 k0 = ~0u, k1 = ~0u, k2 = ~0u, k3 = ~0u;

    const int base = x - R + 64;    // bit offset into padded row
    const int wrd  = base >> 6;     // 0..4
    const int sh   = base & 63;

    // Main scan: straight fully-unrolled 15 clamped rows. No early break ->
    // compiler hoists/pipelines all LDS reads; guarded ins4 keeps late rows
    // cheap. Order within the scan doesn't affect the selected top-4 set.
    #pragma unroll
    for (int rr = 0; rr < WROWS; ++rr) {
        const int rr2 = m0 + rr;
        const u64 lo = win[rr2 * RSTRIDE + wrd];
        const u64 hi = win[rr2 * RSTRIDE + wrd + 1];
        u32 w = (u32)((u64)(((((unsigned __int128)hi) << 64) | lo) >> sh))
                & ((1u << WROWS) - 1);
        const int dy   = y0m + rr - y;
        const int dy2  = dy * dy;
        const int rowx = (y0m + rr) * SZ + x;        // flat idx of (row, x)
        while (w) {
            const int b = __builtin_ctz(w);
            w &= w - 1;
            const int dx  = b - R;
            const u32 d2  = (u32)(dy2 + dx * dx);          // <= 245
            const u32 key = (d2 << 16) | (u32)(rowx + dx);
            ins4(key, k0, k1, k2, k3);
        }
    }

    u64 ks[KNN];
    const u32 in_d2 = k3 >> 16;
    // Exactness: any cell outside (15 main rows ∧ |dx|<=7) has d2 >= 64.
    // Strict '<' so equal-d2 outside ties still trigger the fallback.
    if (in_d2 < (u32)((R + 1) * (R + 1))) {
        ks[0] = k0; ks[1] = k1; ks[2] = k2; ks[3] = k3;  // same bit format
    } else {
        // Secondary fallback (edge pixels, ~1e-3): cap-pruned ring ctz scan
        // over the staged 33-row LDS bitmap, u64 keys (d2 up to 66049).
        // cap = in-window 4th-best d2 (0xFFFF if <4 found) — valid upper
        // bound; a2<=cur / Rx+1 conservatism keeps tie-breaks exact.
        const u64 cap = (u64)in_d2;
        u64 q0 = ~0ull, q1 = ~0ull, q2 = ~0ull, q3 = ~0ull;
        for (int ady = 0; ady < FROWS; ++ady) {
            u64 cur = q3 >> 16;
            if (cap < cur) cur = cap;
            const u64 a2 = (u64)(ady * ady);
            if (a2 > cur) break;          // keep a2 == cur (ties)
            const u64 bound = cur - a2;
            int Rx = (bound >= 65025ull) ? (SZ - 1)
                                         : ((int)sqrtf((float)bound) + 1);
            int xs = x - Rx; if (xs < 0) xs = 0;
            int xe = x + Rx; if (xe > SZ - 1) xe = SZ - 1;
            const int jxs = xs >> 6, jxe = xe >> 6;
            const u64 mlo = (~0ull) << (xs & 63);
            const u64 mhi = (~0ull) >> (63 - (xe & 63));
            #pragma unroll
            for (int s = 0; s < 2; ++s) {
                if (s && ady == 0) continue;
                const int yy = s ? y + ady : y - ady;
                const int rr2 = yy - y0b;
                if (rr2 < 0 || rr2 >= FROWS) continue;   // unstaged: d2>=289
                const int rb = yy * SZ;
                const u64* rw = &win[rr2 * RSTRIDE + 1];
                for (int j = jxs; j <= jxe; ++j) {
                    u64 w = rw[j];
                    if (j == jxs) w &= mlo;
                    if (j == jxe) w &= mhi;
                    while (w) {
                        const int b = __builtin_ctzll(w);
                        w &= w - 1;
                        const int xx = (j << 6) + b;
                        const int dxx = xx - x;
                        const u64 d2 = a2 + (u64)(dxx * dxx);
                        ins4_64((d2 << 16) | (u32)(rb + xx), q0, q1, q2, q3);
                    }
                }
            }
        }
        // Cells outside the staged rows have |dy| >= 17 -> d2 >= 289.
        if ((q3 >> 16) < 289ull) {
            ks[0] = q0; ks[1] = q1; ks[2] = q2; ks[3] = q3;
        } else {
            // Tertiary (correctness guarantee; ~never fires): full-image
            // cap-pruned ring ctz scan over the global bitmap, u64 keys.
            const u64 cap2 = q3 >> 16;
            u64 t0 = ~0ull, t1 = ~0ull, t2 = ~0ull, t3 = ~0ull;
            for (int ady = 0; ady < SZ; ++ady) {
                u64 cur = t3 >> 16;
                if (cap2 < cur) cur = cap2;
                const u64 a2 = (u64)(ady * ady);
                if (a2 > cur) break;
                const u64 bound = cur - a2;
                int Rx = (bound >= 65025ull) ? (SZ - 1)
                                             : ((int)sqrtf((float)bound) + 1);
                int xs = x - Rx; if (xs < 0) xs = 0;
                int xe = x + Rx; if (xe > SZ - 1) xe = SZ - 1;
                const int jxs = xs >> 6, jxe = xe >> 6;
                const u64 mlo = (~0ull) << (xs & 63);
                const u64 mhi = (~0ull) >> (63 - (xe & 63));
                for (int s = 0; s < 2; ++s) {
                    if (s && ady == 0) continue;
                    const int yy = s ? y + ady : y - ady;
                    if (yy < 0 || yy > SZ - 1) continue;
                    const int rb = yy * SZ;
                    for (int j = jxs; j <= jxe; ++j) {
                        u64 w = bmc[yy * 4 + j];
                        if (j == jxs) w &= mlo;
                        if (j == jxe) w &= mhi;
                        while (w) {
                            const int b = __builtin_ctzll(w);
                            w &= w - 1;
                            const int xx = (j << 6) + b;
                            const int dxx = xx - x;
                            const u64 d2 = a2 + (u64)(dxx * dxx);
                            ins4_64((d2 << 16) | (u32)(rb + xx),
                                    t0, t1, t2, t3);
                        }
                    }
                }
            }
            ks[0] = t0; ks[1] = t1; ks[2] = t2; ks[3] = t3;
        }
    }

    // Weighted sum in top_k order (ascending (d2, idx)), matching reference.
    float num = 0.0f, den = 0.0f;
    #pragma unroll
    for (int i = 0; i < KNN; ++i) {
        const int idx = (int)(ks[i] & 0xFFFFull);
        const int d2i = (int)(ks[i] >> 16);
        const float dist = sqrtf((float)d2i * (1.0f / 65536.0f));
        num += img[idx] * dist;
        den += dist;
    }
    outc[pix] = num / den;
}

extern "C" void kernel_launch(void* const* d_in, const int* in_sizes, int n_in,
                              void* d_out, int out_size, void* d_ws, size_t ws_size,
                              hipStream_t stream) {
    const float* img = (const float*)d_in[0];   // coded: [1,1,256,256] f32
    const int*   lut = (const int*)d_in[1];     // lookup_table: [256,256] i32
    float*       out = (float*)d_out;           // [1,8,256,256] f32
    u64*         bm  = (u64*)d_ws;              // 64 KB bitmaps

    build_bitmaps<<<dim3(SZ), dim3(256), 0, stream>>>(lut, bm);
    knn_fill<<<dim3(SZ, NUM_CHANNELS), dim3(256), 0, stream>>>(img, bm, out);
}

// Round 11
// 73.352 us; speedup vs baseline: 1.0277x; 1.0187x over previous
//
#include <hip/hip_runtime.h>
#include <math.h>

#define SZ 256
#define KNN 4
#define NUM_CHANNELS 8
#define R 7                  // main window half-width; exact iff 4th d2 < 64
#define WROWS (2 * R + 1)    // 15 main rows (clamped to image)
#define FR 16                // staged row half-range
#define FROWS (2 * FR + 1)   // 33 staged rows; unstaged rows have d2 >= 289
#define RSTRIDE 6            // LDS row: [zero pad][4 words][zero pad]

typedef unsigned long long u64;
typedef unsigned int u32;

// Guarded branchless insert into ascending sorted 4 (u32 keys).
// key = (d2 << 16) | flat_idx; main-loop d2 <= 245 -> no overflow.
// Matches jax.lax.top_k ordering incl. lower-index tie-break.
// Guard: key >= k3 makes the network a provable no-op -> skip (exec-masked;
// single flat divergence level, straight-line body).
__device__ __forceinline__ void ins4(u32 key, u32& k0, u32& k1,
                                     u32& k2, u32& k3) {
    if (key < k3) {
        u32 m;
        m = (k2 > key) ? k2 : key;  k3 = (k3 < m) ? k3 : m;   // old k2
        m = (k1 > key) ? k1 : key;  k2 = (k2 < m) ? k2 : m;   // old k1
        m = (k0 > key) ? k0 : key;  k1 = (k1 < m) ? k1 : m;   // old k0
        k0 = (k0 < key) ? k0 : key;
    }
}

// u64 variant for fallbacks (d2 up to 130050 would overflow a u32 key).
__device__ __forceinline__ void ins4_64(u64 key, u64& k0, u64& k1,
                                        u64& k2, u64& k3) {
    if (key < k3) {
        u64 m;
        m = (k2 > key) ? k2 : key;  k3 = (k3 < m) ? k3 : m;
        m = (k1 > key) ? k1 : key;  k2 = (k2 < m) ? k2 : m;
        m = (k0 > key) ? k0 : key;  k1 = (k1 < m) ? k1 : m;
        k0 = (k0 < key) ? k0 : key;
    }
}

// Pass 1: per-channel occupancy bitmaps via wave ballot.
// bm layout: u64[NUM_CHANNELS][SZ][4]; word j covers x in [j*64, j*64+64).
__global__ __launch_bounds__(256) void build_bitmaps(
    const int* __restrict__ lut,
    u64* __restrict__ bm)
{
    const int y = blockIdx.x;
    const int x = threadIdx.x;
    const int v = lut[y * SZ + x];
    const int lane = x & 63;
    const int w64 = x >> 6;
    #pragma unroll
    for (int c = 1; c <= NUM_CHANNELS; ++c) {
        u64 bal = __ballot(v == c);
        if (lane == 0) bm[(size_t)(c - 1) * (SZ * 4) + y * 4 + w64] = bal;
    }
}

// Pass 2: stage 33 clamped rows from the global bitmap into LDS; wave-uniform
// |dy|-ordered 15-row scan (u32 keys, guarded insert) with __all early break;
// rare LDS secondary fallback (u64 keys); ~never tertiary (global bitmap).
__global__ __launch_bounds__(256) void knn_fill(
    const float* __restrict__ img,
    const u64*   __restrict__ bm,
    float*       __restrict__ out)
{
    __shared__ u64 win[FROWS * RSTRIDE];   // 1584 B padded window bitmap

    const int x   = threadIdx.x;
    const int y   = blockIdx.x;            // block-uniform -> uniform loops
    const int ch  = blockIdx.y;
    const int tid = threadIdx.x;
    const u64* bmc = bm + (size_t)ch * (SZ * 4);

    // Clamped staged-window start (33 full in-image rows).
    int y0b = y - FR;
    if (y0b < 0) y0b = 0;
    if (y0b > SZ - FROWS) y0b = SZ - FROWS;
    // Clamped main-window start (15 full in-image rows).
    int y0m = y - R;
    if (y0m < 0) y0m = 0;
    if (y0m > SZ - WROWS) y0m = SZ - WROWS;
    const int m0 = y0m - y0b;              // main rows offset in staged buf

    // Zero the 66 pad words; load the 132 contiguous bitmap words.
    if (tid < FROWS * 2) win[(tid >> 1) * RSTRIDE + (tid & 1) * 5] = 0;
    if (tid < FROWS * 4) {
        const int rr = tid >> 2, j = tid & 3;
        win[rr * RSTRIDE + 1 + j] = bmc[(y0b + rr) * 4 + j];
    }
    __syncthreads();

    const int pix = y * SZ + x;
    float* outc = out + (size_t)ch * (SZ * SZ);

    if ((win[(y - y0b) * RSTRIDE + 1 + (x >> 6)] >> (x & 63)) & 1ull) {
        outc[pix] = img[pix];
        return;
    }

    u32 k0 = ~0u, k1 = ~0u, k2 = ~0u, k3 = ~0u;

    const int base = x - R + 64;    // bit offset into padded row
    const int wrd  = base >> 6;     // 0..4
    const int sh   = base & 63;

    // Main scan, rows ordered by |dy| (block-uniform control flow).
    for (int ady = 0; ady < WROWS; ++ady) {
        #pragma unroll
        for (int s = 0; s < 2; ++s) {
            if (s && ady == 0) continue;
            const int yy = s ? y + ady : y - ady;
            const int rr = yy - y0m;
            if (rr < 0 || rr >= WROWS) continue;     // outside clamped window
            const int rr2 = m0 + rr;
            const u64 lo = win[rr2 * RSTRIDE + wrd];
            const u64 hi = win[rr2 * RSTRIDE + wrd + 1];
            u32 w = (u32)((u64)(((((unsigned __int128)hi) << 64) | lo) >> sh))
                    & ((1u << WROWS) - 1);
            const int dy2  = ady * ady;
            const int rowx = yy * SZ + x;            // flat idx of (row, x)
            while (w) {
                const int b = __builtin_ctz(w);
                w &= w - 1;
                const int dx  = b - R;
                const u32 d2  = (u32)(dy2 + dx * dx);      // <= 245
                const u32 key = (d2 << 16) | (u32)(rowx + dx);
                ins4(key, k0, k1, k2, k3);
            }
        }
        // Remaining window rows have |dy| >= ady+1 -> candidate d2 >=
        // (ady+1)^2 > lane's k3_d2 -> key > k3 -> insert is a no-op.
        // Strict '<' preserves tie-break exactness.
        if (__all((k3 >> 16) < (u32)((ady + 1) * (ady + 1)))) break;
    }

    u64 ks[KNN];
    const u32 in_d2 = k3 >> 16;
    // Exactness: any cell outside (15 main rows ∧ |dx|<=7) has d2 >= 64.
    if (in_d2 < (u32)((R + 1) * (R + 1))) {
        ks[0] = k0; ks[1] = k1; ks[2] = k2; ks[3] = k3;  // same bit format
    } else {
        // Secondary fallback (edge pixels, ~1e-3): cap-pruned ring ctz scan
        // over the staged 33-row LDS bitmap, u64 keys (d2 up to 66049).
        // cap = in-window 4th-best d2 (0xFFFF if <4 found) — valid upper
        // bound; a2<=cur / Rx+1 conservatism keeps tie-breaks exact.
        const u64 cap = (u64)in_d2;
        u64 q0 = ~0ull, q1 = ~0ull, q2 = ~0ull, q3 = ~0ull;
        for (int ady = 0; ady < FROWS; ++ady) {
            u64 cur = q3 >> 16;
            if (cap < cur) cur = cap;
            const u64 a2 = (u64)(ady * ady);
            if (a2 > cur) break;          // keep a2 == cur (ties)
            const u64 bound = cur - a2;
            int Rx = (bound >= 65025ull) ? (SZ - 1)
                                         : ((int)sqrtf((float)bound) + 1);
            int xs = x - Rx; if (xs < 0) xs = 0;
            int xe = x + Rx; if (xe > SZ - 1) xe = SZ - 1;
            const int jxs = xs >> 6, jxe = xe >> 6;
            const u64 mlo = (~0ull) << (xs & 63);
            const u64 mhi = (~0ull) >> (63 - (xe & 63));
            #pragma unroll
            for (int s = 0; s < 2; ++s) {
                if (s && ady == 0) continue;
                const int yy = s ? y + ady : y - ady;
                const int rr2 = yy - y0b;
                if (rr2 < 0 || rr2 >= FROWS) continue;   // unstaged: d2>=289
                const int rb = yy * SZ;
                const u64* rw = &win[rr2 * RSTRIDE + 1];
                for (int j = jxs; j <= jxe; ++j) {
                    u64 w = rw[j];
                    if (j == jxs) w &= mlo;
                    if (j == jxe) w &= mhi;
                    while (w) {
                        const int b = __builtin_ctzll(w);
                        w &= w - 1;
                        const int xx = (j << 6) + b;
                        const int dxx = xx - x;
                        const u64 d2 = a2 + (u64)(dxx * dxx);
                        ins4_64((d2 << 16) | (u32)(rb + xx), q0, q1, q2, q3);
                    }
                }
            }
        }
        // Cells outside the staged rows have |dy| >= 17 -> d2 >= 289.
        if ((q3 >> 16) < 289ull) {
            ks[0] = q0; ks[1] = q1; ks[2] = q2; ks[3] = q3;
        } else {
            // Tertiary (correctness guarantee; ~never fires): full-image
            // cap-pruned ring ctz scan over the global bitmap, u64 keys.
            const u64 cap2 = q3 >> 16;
            u64 t0 = ~0ull, t1 = ~0ull, t2 = ~0ull, t3 = ~0ull;
            for (int ady = 0; ady < SZ; ++ady) {
                u64 cur = t3 >> 16;
                if (cap2 < cur) cur = cap2;
                const u64 a2 = (u64)(ady * ady);
                if (a2 > cur) break;
                const u64 bound = cur - a2;
                int Rx = (bound >= 65025ull) ? (SZ - 1)
                                             : ((int)sqrtf((float)bound) + 1);
                int xs = x - Rx; if (xs < 0) xs = 0;
                int xe = x + Rx; if (xe > SZ - 1) xe = SZ - 1;
                const int jxs = xs >> 6, jxe = xe >> 6;
                const u64 mlo = (~0ull) << (xs & 63);
                const u64 mhi = (~0ull) >> (63 - (xe & 63));
                for (int s = 0; s < 2; ++s) {
                    if (s && ady == 0) continue;
                    const int yy = s ? y + ady : y - ady;
                    if (yy < 0 || yy > SZ - 1) continue;
                    const int rb = yy * SZ;
                    for (int j = jxs; j <= jxe; ++j) {
                        u64 w = bmc[yy * 4 + j];
                        if (j == jxs) w &= mlo;
                        if (j == jxe) w &= mhi;
                        while (w) {
                            const int b = __builtin_ctzll(w);
                            w &= w - 1;
                            const int xx = (j << 6) + b;
                            const int dxx = xx - x;
                            const u64 d2 = a2 + (u64)(dxx * dxx);
                            ins4_64((d2 << 16) | (u32)(rb + xx),
                                    t0, t1, t2, t3);
                        }
                    }
                }
            }
            ks[0] = t0; ks[1] = t1; ks[2] = t2; ks[3] = t3;
        }
    }

    // Weighted sum in top_k order (ascending (d2, idx)), matching reference.
    float num = 0.0f, den = 0.0f;
    #pragma unroll
    for (int i = 0; i < KNN; ++i) {
        const int idx = (int)(ks[i] & 0xFFFFull);
        const int d2i = (int)(ks[i] >> 16);
        const float dist = sqrtf((float)d2i * (1.0f / 65536.0f));
        num += img[idx] * dist;
        den += dist;
    }
    outc[pix] = num / den;
}

extern "C" void kernel_launch(void* const* d_in, const int* in_sizes, int n_in,
                              void* d_out, int out_size, void* d_ws, size_t ws_size,
                              hipStream_t stream) {
    const float* img = (const float*)d_in[0];   // coded: [1,1,256,256] f32
    const int*   lut = (const int*)d_in[1];     // lookup_table: [256,256] i32
    float*       out = (float*)d_out;           // [1,8,256,256] f32
    u64*         bm  = (u64*)d_ws;              // 64 KB bitmaps

    build_bitmaps<<<dim3(SZ), dim3(256), 0, stream>>>(lut, bm);
    knn_fill<<<dim3(SZ, NUM_CHANNELS), dim3(256), 0, stream>>>(img, bm, out);
}

// Round 12
// 72.148 us; speedup vs baseline: 1.0448x; 1.0167x over previous
//
#include <hip/hip_runtime.h>
#include <math.h>

#define SZ 256
#define KNN 4
#define NUM_CHANNELS 8
#define R 7                  // main window half-width; exact iff 4th d2 < 64
#define WROWS (2 * R + 1)    // 15 main rows (clamped to image)
#define FR 16                // staged row half-range
#define FROWS (2 * FR + 1)   // 33 staged rows; unstaged rows have d2 >= 289
#define RSTRIDE 6            // LDS row: [zero pad][4 words][zero pad]

typedef unsigned long long u64;
typedef unsigned int u32;

// Branchless insert into ascending sorted 4 (u32 keys).
// key = (d2 << 16) | flat_idx; main-loop d2 <= 245 -> no overflow.
// Matches jax.lax.top_k ordering incl. lower-index tie-break.
// NOTE (R11 post-mortem): the guarded variant measured neutral-to-worse;
// unguarded is the empirical best (R8 = 72.2 us).
__device__ __forceinline__ void ins4(u32 key, u32& k0, u32& k1,
                                     u32& k2, u32& k3) {
    u32 m;
    m = (k2 > key) ? k2 : key;  k3 = (k3 < m) ? k3 : m;   // old k2
    m = (k1 > key) ? k1 : key;  k2 = (k2 < m) ? k2 : m;   // old k1
    m = (k0 > key) ? k0 : key;  k1 = (k1 < m) ? k1 : m;   // old k0
    k0 = (k0 < key) ? k0 : key;
}

// u64 variant for fallbacks (d2 up to 130050 would overflow a u32 key).
__device__ __forceinline__ void ins4_64(u64 key, u64& k0, u64& k1,
                                        u64& k2, u64& k3) {
    if (key < k3) {
        u64 m;
        m = (k2 > key) ? k2 : key;  k3 = (k3 < m) ? k3 : m;
        m = (k1 > key) ? k1 : key;  k2 = (k2 < m) ? k2 : m;
        m = (k0 > key) ? k0 : key;  k1 = (k1 < m) ? k1 : m;
        k0 = (k0 < key) ? k0 : key;
    }
}

// Pass 1: per-channel occupancy bitmaps via wave ballot.
// bm layout: u64[NUM_CHANNELS][SZ][4]; word j covers x in [j*64, j*64+64).
// One ballot pass over lut (256 blocks) is strictly cheaper than per-block
// ballot staging in the fill kernel (R7/R9 both regressed).
__global__ __launch_bounds__(256) void build_bitmaps(
    const int* __restrict__ lut,
    u64* __restrict__ bm)
{
    const int y = blockIdx.x;
    const int x = threadIdx.x;
    const int v = lut[y * SZ + x];
    const int lane = x & 63;
    const int w64 = x >> 6;
    #pragma unroll
    for (int c = 1; c <= NUM_CHANNELS; ++c) {
        u64 bal = __ballot(v == c);
        if (lane == 0) bm[(size_t)(c - 1) * (SZ * 4) + y * 4 + w64] = bal;
    }
}

// Pass 2: stage 33 clamped rows from the global bitmap into LDS; wave-uniform
// |dy|-ordered 15-row scan (u32 keys) with __all early break; rare LDS
// secondary fallback (u64 keys); ~never tertiary over the global bitmap.
__global__ __launch_bounds__(256) void knn_fill(
    const float* __restrict__ img,
    const u64*   __restrict__ bm,
    float*       __restrict__ out)
{
    __shared__ u64 win[FROWS * RSTRIDE];   // 1584 B padded window bitmap

    const int x   = threadIdx.x;
    const int y   = blockIdx.x;            // block-uniform -> uniform loops
    const int ch  = blockIdx.y;
    const int tid = threadIdx.x;
    const u64* bmc = bm + (size_t)ch * (SZ * 4);

    // Clamped staged-window start (33 full in-image rows).
    int y0b = y - FR;
    if (y0b < 0) y0b = 0;
    if (y0b > SZ - FROWS) y0b = SZ - FROWS;
    // Clamped main-window start (15 full in-image rows).
    int y0m = y - R;
    if (y0m < 0) y0m = 0;
    if (y0m > SZ - WROWS) y0m = SZ - WROWS;
    const int m0 = y0m - y0b;              // main rows offset in staged buf

    // Zero the 66 pad words; load the 132 contiguous bitmap words.
    if (tid < FROWS * 2) win[(tid >> 1) * RSTRIDE + (tid & 1) * 5] = 0;
    if (tid < FROWS * 4) {
        const int rr = tid >> 2, j = tid & 3;
        win[rr * RSTRIDE + 1 + j] = bmc[(y0b + rr) * 4 + j];
    }
    __syncthreads();

    const int pix = y * SZ + x;
    float* outc = out + (size_t)ch * (SZ * SZ);

    if ((win[(y - y0b) * RSTRIDE + 1 + (x >> 6)] >> (x & 63)) & 1ull) {
        outc[pix] = img[pix];
        return;
    }

    u32 k0 = ~0u, k1 = ~0u, k2 = ~0u, k3 = ~0u;

    const int base = x - R + 64;    // bit offset into padded row
    const int wrd  = base >> 6;     // 0..4
    const int sh   = base & 63;

    // Main scan, rows ordered by |dy| (block-uniform control flow).
    // The data-dependent __all break saves ~25% of row iterations and beats
    // a fully-unrolled straight scan (R10 regressed).
    for (int ady = 0; ady < WROWS; ++ady) {
        #pragma unroll
        for (int s = 0; s < 2; ++s) {
            if (s && ady == 0) continue;
            const int yy = s ? y + ady : y - ady;
            const int rr = yy - y0m;
            if (rr < 0 || rr >= WROWS) continue;     // outside clamped window
            const int rr2 = m0 + rr;
            const u64 lo = win[rr2 * RSTRIDE + wrd];
            const u64 hi = win[rr2 * RSTRIDE + wrd + 1];
            u32 w = (u32)((u64)(((((unsigned __int128)hi) << 64) | lo) >> sh))
                    & ((1u << WROWS) - 1);
            const int dy2  = ady * ady;
            const int rowx = yy * SZ + x;            // flat idx of (row, x)
            while (w) {
                const int b = __builtin_ctz(w);
                w &= w - 1;
                const int dx  = b - R;
                const u32 d2  = (u32)(dy2 + dx * dx);      // <= 245
                const u32 key = (d2 << 16) | (u32)(rowx + dx);
                ins4(key, k0, k1, k2, k3);
            }
        }
        // Remaining window rows have |dy| >= ady+1 -> candidate d2 >=
        // (ady+1)^2 > lane's k3_d2 -> key > k3 -> insert is a no-op.
        // Strict '<' preserves tie-break exactness.
        if (__all((k3 >> 16) < (u32)((ady + 1) * (ady + 1)))) break;
    }

    u64 ks[KNN];
    const u32 in_d2 = k3 >> 16;
    // Exactness: any cell outside (15 main rows ∧ |dx|<=7) has d2 >= 64.
    if (in_d2 < (u32)((R + 1) * (R + 1))) {
        ks[0] = k0; ks[1] = k1; ks[2] = k2; ks[3] = k3;  // same bit format
    } else {
        // Secondary fallback (edge pixels, ~1e-3): cap-pruned ring ctz scan
        // over the staged 33-row LDS bitmap, u64 keys (d2 up to 66049).
        // cap = in-window 4th-best d2 (0xFFFF if <4 found) — valid upper
        // bound; a2<=cur / Rx+1 conservatism keeps tie-breaks exact.
        const u64 cap = (u64)in_d2;
        u64 q0 = ~0ull, q1 = ~0ull, q2 = ~0ull, q3 = ~0ull;
        for (int ady = 0; ady < FROWS; ++ady) {
            u64 cur = q3 >> 16;
            if (cap < cur) cur = cap;
            const u64 a2 = (u64)(ady * ady);
            if (a2 > cur) break;          // keep a2 == cur (ties)
            const u64 bound = cur - a2;
            int Rx = (bound >= 65025ull) ? (SZ - 1)
                                         : ((int)sqrtf((float)bound) + 1);
            int xs = x - Rx; if (xs < 0) xs = 0;
            int xe = x + Rx; if (xe > SZ - 1) xe = SZ - 1;
            const int jxs = xs >> 6, jxe = xe >> 6;
            const u64 mlo = (~0ull) << (xs & 63);
            const u64 mhi = (~0ull) >> (63 - (xe & 63));
            #pragma unroll
            for (int s = 0; s < 2; ++s) {
                if (s && ady == 0) continue;
                const int yy = s ? y + ady : y - ady;
                const int rr2 = yy - y0b;
                if (rr2 < 0 || rr2 >= FROWS) continue;   // unstaged: d2>=289
                const int rb = yy * SZ;
                const u64* rw = &win[rr2 * RSTRIDE + 1];
                for (int j = jxs; j <= jxe; ++j) {
                    u64 w = rw[j];
                    if (j == jxs) w &= mlo;
                    if (j == jxe) w &= mhi;
                    while (w) {
                        const int b = __builtin_ctzll(w);
                        w &= w - 1;
                        const int xx = (j << 6) + b;
                        const int dxx = xx - x;
                        const u64 d2 = a2 + (u64)(dxx * dxx);
                        ins4_64((d2 << 16) | (u32)(rb + xx), q0, q1, q2, q3);
                    }
                }
            }
        }
        // Cells outside the staged rows have |dy| >= 17 -> d2 >= 289.
        if ((q3 >> 16) < 289ull) {
            ks[0] = q0; ks[1] = q1; ks[2] = q2; ks[3] = q3;
        } else {
            // Tertiary (correctness guarantee; ~never fires): full-image
            // cap-pruned ring ctz scan over the global bitmap, u64 keys.
            const u64 cap2 = q3 >> 16;
            u64 t0 = ~0ull, t1 = ~0ull, t2 = ~0ull, t3 = ~0ull;
            for (int ady = 0; ady < SZ; ++ady) {
                u64 cur = t3 >> 16;
                if (cap2 < cur) cur = cap2;
                const u64 a2 = (u64)(ady * ady);
                if (a2 > cur) break;
                const u64 bound = cur - a2;
                int Rx = (bound >= 65025ull) ? (SZ - 1)
                                             : ((int)sqrtf((float)bound) + 1);
                int xs = x - Rx; if (xs < 0) xs = 0;
                int xe = x + Rx; if (xe > SZ - 1) xe = SZ - 1;
                const int jxs = xs >> 6, jxe = xe >> 6;
                const u64 mlo = (~0ull) << (xs & 63);
                const u64 mhi = (~0ull) >> (63 - (xe & 63));
                for (int s = 0; s < 2; ++s) {
                    if (s && ady == 0) continue;
                    const int yy = s ? y + ady : y - ady;
                    if (yy < 0 || yy > SZ - 1) continue;
                    const int rb = yy * SZ;
                    for (int j = jxs; j <= jxe; ++j) {
                        u64 w = bmc[yy * 4 + j];
                        if (j == jxs) w &= mlo;
                        if (j == jxe) w &= mhi;
                        while (w) {
                            const int b = __builtin_ctzll(w);
                            w &= w - 1;
                            const int xx = (j << 6) + b;
                            const int dxx = xx - x;
                            const u64 d2 = a2 + (u64)(dxx * dxx);
                            ins4_64((d2 << 16) | (u32)(rb + xx),
                                    t0, t1, t2, t3);
                        }
                    }
                }
            }
            ks[0] = t0; ks[1] = t1; ks[2] = t2; ks[3] = t3;
        }
    }

    // Weighted sum in top_k order (ascending (d2, idx)), matching reference.
    float num = 0.0f, den = 0.0f;
    #pragma unroll
    for (int i = 0; i < KNN; ++i) {
        const int idx = (int)(ks[i] & 0xFFFFull);
        const int d2i = (int)(ks[i] >> 16);
        const float dist = sqrtf((float)d2i * (1.0f / 65536.0f));
        num += img[idx] * dist;
        den += dist;
    }
    outc[pix] = num / den;
}

extern "C" void kernel_launch(void* const* d_in, const int* in_sizes, int n_in,
                              void* d_out, int out_size, void* d_ws, size_t ws_size,
                              hipStream_t stream) {
    const float* img = (const float*)d_in[0];   // coded: [1,1,256,256] f32
    const int*   lut = (const int*)d_in[1];     // lookup_table: [256,256] i32
    float*       out = (float*)d_out;           // [1,8,256,256] f32
    u64*         bm  = (u64*)d_ws;              // 64 KB bitmaps

    build_bitmaps<<<dim3(SZ), dim3(256), 0, stream>>>(lut, bm);
    knn_fill<<<dim3(SZ, NUM_CHANNELS), dim3(256), 0, stream>>>(img, bm, out);
}